// Round 14
// baseline (312.820 us; speedup 1.0000x reference)
//
#include <hip/hip_runtime.h>
#include <hip/hip_bf16.h>

#define TXT   512
#define REDUX 64
#define IMG   2048
#define REFN  512
#define NC    2
#define SEQ   3168
#define DH    128
#define NH    24
#define TRE   576
#define TRI   2624
#define TRIR  3136
#define SCALE 0.08838834764831845f
#define L2E   1.4426950408889634f
#define QSC   (SCALE * L2E)          // scale folded with log2(e)
#define C100  (100.0f * L2E)         // 144.2695
#define CREF  (98.5f * L2E)          // 142.1055
#define THR2  (4.0f * L2E)           // defer-max threshold in log2 units

using f32x4  = __attribute__((ext_vector_type(4))) float;
using short8 = __attribute__((ext_vector_type(8))) short;

__device__ inline short f2bf(float x) {
    union { __hip_bfloat16 b; short s; } u;
    u.b = __float2bfloat16(x);
    return u.s;
}

__device__ inline void gload16(const short* g, short* l) {
    __builtin_amdgcn_global_load_lds(
        (const __attribute__((address_space(1))) unsigned int*)g,
        (__attribute__((address_space(3))) unsigned int*)l, 16, 0, 0);
}

// ---------------- fused pre-pass: K f32->bf16 linear, V f32->bf16 transposed+permuted ----
__global__ void cvt_kv_kernel(const float* __restrict__ K, const float* __restrict__ V,
                              short* __restrict__ Kb, short* __restrict__ Vt) {
    const int h   = blockIdx.y;
    const int tid = threadIdx.x;
    {
        const int base = ((h * SEQ + blockIdx.x * 16) * DH) >> 2;   // float4 idx
        #pragma unroll
        for (int j = 0; j < 2; ++j) {
            const int i = base + tid + j * 256;
            const float4 v = ((const float4*)K)[i];
            short4 o;
            o.x = f2bf(v.x); o.y = f2bf(v.y); o.z = f2bf(v.z); o.w = f2bf(v.w);
            ((short4*)Kb)[i] = o;
        }
    }
    {
        const int s8 = blockIdx.x * 2 + (tid >> 7);
        const int d  = tid & 127;
        const int s0 = s8 * 8;                       // 8 consecutive keys
        const float* src = V + ((size_t)h * SEQ + s0) * DH + d;
        short8 w;
        #pragma unroll
        for (int j = 0; j < 8; ++j) w[j] = f2bf(src[j * DH]);
        // lambda-permuted positions within the 64-key tile
        const int tb   = s0 & ~63;
        const int j0   = s0 & 63;
        const int ks2  = j0 >> 5;
        const int jm   = j0 & 15;
        const int hi   = (j0 >> 4) & 1;
        const int pos0 = ks2 * 32 + (jm >> 2) * 8 + hi * 4;
        short* dst = Vt + ((size_t)h * DH + d) * SEQ + tb;
        short4 lo4, hi4;
        lo4.x = w[0]; lo4.y = w[1]; lo4.z = w[2]; lo4.w = w[3];
        hi4.x = w[4]; hi4.y = w[5]; hi4.z = w[6]; hi4.w = w[7];
        *(short4*)(dst + pos0)     = lo4;
        *(short4*)(dst + pos0 + 8) = hi4;
    }
}

// ---------------- MFMA flash attention: swapped-QK, 8 waves = 4 q-groups x 2 key-halves ----
// wave w: qg = w&3 (q rows qg*32..+31), kh = w>>2 (keys kh*32..+31 of each 64-key tile).
// Merge epilogue fully ALIASES the dead 32KB Ks/Vs region (2 rounds x 2 qg x 16KB) so
// LDS stays ~33.8KB -> 4 blocks/CU (R13's 65KB buffer capped residency at 2 -> 313us).
__global__ __launch_bounds__(512, 2)
void attn_mfma(const float* __restrict__ Q, const short* __restrict__ Kb,
               const short* __restrict__ Vtg, const float* __restrict__ ref_mask,
               const float* __restrict__ routing, float* __restrict__ out)
{
    __shared__ short smem[17408];      // 32KB K/V (loop) | epilogue: 2x16KB acc + 1KB m/l
    short* Ks = smem;                  // [key][chunk^(key&7)] bf16, 8192 shorts
    short* Vs = smem + 8192;           // [d][kc^(d&7)] bf16 (lambda-permuted), 8192 shorts
    float* accA = (float*)smem;        // epilogue: 2 chunks x 4096 floats (aliases Ks+Vs)
    float* mlA  = (float*)(smem + 16384);  // epilogue: 128 floats m/l (separate 1KB)

    const int bid  = blockIdx.x;
    const int h    = bid % NH;          // same head -> same (bid%8) -> same XCD
    const int bx   = bid / NH;          // 0..25, heavy blocks dispatch first
    const int tid  = threadIdx.x;
    const int wave = tid >> 6, lane = tid & 63;
    const int g    = lane >> 4, l4 = lane & 15;
    const int qg   = wave & 3;          // q-group
    const int kh   = wave >> 2;         // key half

    int qbase, ks0 = 0, ntiles;
    bool masked = false, router = false;
    if (bx < 21)       { qbase = bx * 128; ntiles = 49; masked = true; }
    else if (bx == 21) { qbase = TRIR; ntiles = 33; router = true; }
    else {
        const int b2 = bx - 22;
        qbase = TRI + b2 * 128;
        ks0 = TRI + (b2 >> 1) * 256; ntiles = 4;
    }

    const int rbase = qbase + qg * 32;               // this wave's 32 q rows
    const bool valid = !(masked && rbase >= TRI) && !(router && qg >= 1);

    // ---- staging address precompute (pre-swizzled global source, linear LDS dest) ----
    const short* KbH = Kb  + (size_t)h * SEQ * DH;
    const short* VtH = Vtg + (size_t)h * DH * SEQ;
    int koff[2], vD[2], vKC[2], voff[2];
    #pragma unroll
    for (int j = 0; j < 2; ++j) {
        const int ci = tid + j * 512;
        const int kk = ci >> 4, kc = ci & 15;
        koff[j] = kk * 128 + ((kc ^ (kk & 7)) << 3);
        const int vd = ci >> 3, vk = ci & 7;
        vD[j] = vd; vKC[j] = vk;
        voff[j] = vd * SEQ + ((vk ^ (vd & 7)) << 3);
    }
    short* ksd0 = Ks + (size_t)(wave * 64) * 8;
    short* ksd1 = Ks + (size_t)(512 + wave * 64) * 8;
    short* vsd0 = Vs + (size_t)(wave * 64) * 8;
    short* vsd1 = Vs + (size_t)(512 + wave * 64) * 8;

    // ---- Q fragments (pre-scaled to log2 domain): qA[qt][ks], row = qt*16+l4 ----
    short8 qA[2][4];
    if (valid) {
        #pragma unroll
        for (int qt = 0; qt < 2; ++qt) {
            const int q = rbase + qt * 16 + l4;
            const float* qp = Q + ((size_t)h * SEQ + q) * DH;
            #pragma unroll
            for (int ks = 0; ks < 4; ++ks) {
                const float4 a = *(const float4*)(qp + ks * 32 + g * 8);
                const float4 b = *(const float4*)(qp + ks * 32 + g * 8 + 4);
                short8 f;
                f[0] = f2bf(a.x * QSC); f[1] = f2bf(a.y * QSC);
                f[2] = f2bf(a.z * QSC); f[3] = f2bf(a.w * QSC);
                f[4] = f2bf(b.x * QSC); f[5] = f2bf(b.y * QSC);
                f[6] = f2bf(b.z * QSC); f[7] = f2bf(b.w * QSC);
                qA[qt][ks] = f;
            }
        }
    }

    f32x4 acc[2][8] = {};
    float m_run[2] = {-3.0e38f, -3.0e38f}, l_run[2] = {0.f, 0.f};
    const int bsrc = (lane >> 4) << 2;               // shuffle source base g*4

    for (int t = 0; t < ntiles; ++t) {
        const int kt = masked ? t * 64
                     : (router ? (t < 32 ? TRE + t * 64 : TRIR) : ks0 + t * 64);
        const bool tail = router && (t == 32);       // only 32 of 64 keys valid
        __syncthreads();                             // A: previous tile consumed
        const short* kb = KbH + (size_t)kt * DH;
        const short* vb = VtH + kt;
        {
            const int ko0 = tail ? (koff[0] & 4095) : koff[0];
            const int ko1 = tail ? (koff[1] & 4095) : koff[1];
            gload16(kb + ko0, ksd0);
            gload16(kb + ko1, ksd1);
            const int vo0 = tail ? (vD[0] * SEQ + (((vKC[0] ^ (vD[0] & 7)) & 3) << 3)) : voff[0];
            const int vo1 = tail ? (vD[1] * SEQ + (((vKC[1] ^ (vD[1] & 7)) & 3) << 3)) : voff[1];
            gload16(vb + vo0, vsd0);
            gload16(vb + vo1, vsd1);
        }
        __syncthreads();                             // B: drains vmcnt + barrier

        if (!valid) continue;

        // ---- QK^T swapped: s[qt][nt][r] = S[key = kh*32+nt*16+g*4+r][q = rbase+qt*16+l4] ----
        f32x4 s[2][2] = {};
        __builtin_amdgcn_s_setprio(1);
        #pragma unroll
        for (int nt = 0; nt < 2; ++nt) {
            const int key = kh * 32 + nt * 16 + l4;
            #pragma unroll
            for (int ks = 0; ks < 4; ++ks) {
                const short8 kB = *(const short8*)(Ks + key * 128 + (((ks * 4 + g) ^ (key & 7)) << 3));
                s[0][nt] = __builtin_amdgcn_mfma_f32_16x16x32_bf16(kB, qA[0][ks], s[0][nt], 0, 0, 0);
                s[1][nt] = __builtin_amdgcn_mfma_f32_16x16x32_bf16(kB, qA[1][ks], s[1][nt], 0, 0, 0);
            }
        }
        __builtin_amdgcn_s_setprio(0);

        // ---- masks (f32 exact, log2 domain), swapped orientation, per qt ----
        if (masked) {
            if (kt >= TRI) {                         // ref-key tiles
                const int cr = (kt - TRI) >> 8;
                const int j0 = kt - TRI + kh * 32 + g * 4;
                #pragma unroll
                for (int qt = 0; qt < 2; ++qt) {
                    const int q  = rbase + qt * 16 + l4;
                    const bool hr = rbase >= TRE;
                    float radd = 0.f;
                    if (hr) radd = routing[cr * IMG + (q - TRE)] * C100 - C100;
                    #pragma unroll
                    for (int nt = 0; nt < 2; ++nt)
                        #pragma unroll
                        for (int r = 0; r < 4; ++r) {
                            const float rmv = ref_mask[(size_t)(j0 + nt * 16 + r) * TRI + q];
                            s[qt][nt][r] += rmv * C100 - CREF + radd;
                        }
                }
            } else if (kt == TXT) {                  // redux-key tile: cond = key>>5 = kh
                if (rbase >= TRE) {
                    #pragma unroll
                    for (int qt = 0; qt < 2; ++qt) {
                        const int q = rbase + qt * 16 + l4;
                        const float a = routing[kh * IMG + q - TRE] * C100 - C100;
                        #pragma unroll
                        for (int nt = 0; nt < 2; ++nt)
                            #pragma unroll
                            for (int r = 0; r < 4; ++r)
                                s[qt][nt][r] += a;
                    }
                }
            }
        }
        if (tail && kh) {                            // router tail: keys 32..63 invalid
            #pragma unroll
            for (int qt = 0; qt < 2; ++qt)
                #pragma unroll
                for (int nt = 0; nt < 2; ++nt)
                    #pragma unroll
                    for (int r = 0; r < 4; ++r) s[qt][nt][r] = -3.0e38f;
        }

        // ---- softmax per qt over this wave's 32 keys: lane-local + 2 shuffles ----
        float mx[2];
        #pragma unroll
        for (int qt = 0; qt < 2; ++qt) {
            float m0 = fmaxf(fmaxf(s[qt][0][0], s[qt][0][1]), fmaxf(s[qt][0][2], s[qt][0][3]));
            m0 = fmaxf(m0, fmaxf(fmaxf(s[qt][1][0], s[qt][1][1]), fmaxf(s[qt][1][2], s[qt][1][3])));
            m0 = fmaxf(m0, __shfl_xor(m0, 16));
            m0 = fmaxf(m0, __shfl_xor(m0, 32));
            mx[qt] = m0;
        }

        const float gmax = fmaxf(mx[0] - m_run[0], mx[1] - m_run[1]);
        if (__any(gmax > THR2)) {                    // defer-max rescale (rare)
            #pragma unroll
            for (int qt = 0; qt < 2; ++qt) {
                const float mn    = fmaxf(m_run[qt], mx[qt]);
                const float corrq = exp2f(m_run[qt] - mn);
                m_run[qt] = mn;
                l_run[qt] *= corrq;
                f32x4 corr;
                #pragma unroll
                for (int r = 0; r < 4; ++r) corr[r] = __shfl(corrq, bsrc + r);
                #pragma unroll
                for (int nt = 0; nt < 8; ++nt)
                    #pragma unroll
                    for (int r = 0; r < 4; ++r) acc[qt][nt][r] *= corr[r];
            }
        }

        short8 pA[2];                                // [qt], lambda slot order (ks2 = kh)
        #pragma unroll
        for (int qt = 0; qt < 2; ++qt) {
            float rsum = 0.f;
            #pragma unroll
            for (int nt = 0; nt < 2; ++nt)
                #pragma unroll
                for (int r = 0; r < 4; ++r) {
                    s[qt][nt][r] = exp2f(s[qt][nt][r] - m_run[qt]);
                    rsum += s[qt][nt][r];
                }
            rsum += __shfl_xor(rsum, 16);
            rsum += __shfl_xor(rsum, 32);
            l_run[qt] += rsum;
            #pragma unroll
            for (int j = 0; j < 4; ++j) {
                pA[qt][j]     = f2bf(s[qt][0][j]);
                pA[qt][4 + j] = f2bf(s[qt][1][j]);
            }
        }

        // ---- PV: one b128 vB per nt (kc = kh*4+g), shared across both qt ----
        __builtin_amdgcn_s_setprio(1);
        {
            const int kc = kh * 4 + g;
            #pragma unroll
            for (int nt = 0; nt < 8; ++nt) {
                const int d = nt * 16 + l4;
                const short8 vB = *(const short8*)(Vs + d * 64 + ((kc ^ (d & 7)) << 3));
                acc[0][nt] = __builtin_amdgcn_mfma_f32_16x16x32_bf16(pA[0], vB, acc[0][nt], 0, 0, 0);
                acc[1][nt] = __builtin_amdgcn_mfma_f32_16x16x32_bf16(pA[1], vB, acc[1][nt], 0, 0, 0);
            }
        }
        __builtin_amdgcn_s_setprio(0);
    }

    // ---- merge kh=0 / kh=1 partials through the DEAD Ks/Vs LDS, 2 rounds x 2 qg ----
    __syncthreads();                                 // all waves done reading Ks/Vs
    #pragma unroll
    for (int rr = 0; rr < 2; ++rr) {
        if (valid && kh == 1 && (qg >> 1) == rr) {
            float* ab = accA + (qg & 1) * 4096;
            #pragma unroll
            for (int qt = 0; qt < 2; ++qt)
                #pragma unroll
                for (int nt = 0; nt < 8; ++nt)
                    *(f32x4*)(ab + ((qt * 8 + nt) * 64 + lane) * 4) = acc[qt][nt];
            if (g == 0) {
                #pragma unroll
                for (int qt = 0; qt < 2; ++qt) {
                    mlA[(qg & 1) * 32 + qt * 16 + l4]      = m_run[qt];
                    mlA[64 + (qg & 1) * 32 + qt * 16 + l4] = l_run[qt];
                }
            }
        }
        __syncthreads();
        if (valid && kh == 0 && (qg >> 1) == rr) {
            const float* ab = accA + (qg & 1) * 4096;
            #pragma unroll
            for (int qt = 0; qt < 2; ++qt) {
                const float m1 = mlA[(qg & 1) * 32 + qt * 16 + l4];
                const float l1 = mlA[64 + (qg & 1) * 32 + qt * 16 + l4];
                const float mm = fmaxf(m_run[qt], m1);
                const float w0 = exp2f(m_run[qt] - mm);
                const float w1 = exp2f(m1 - mm);
                const float inv = 1.0f / (l_run[qt] * w0 + l1 * w1);
                const float ow0 = w0 * inv, ow1 = w1 * inv;
                f32x4 v0, v1;
                #pragma unroll
                for (int r = 0; r < 4; ++r) {
                    v0[r] = __shfl(ow0, bsrc + r);
                    v1[r] = __shfl(ow1, bsrc + r);
                }
                #pragma unroll
                for (int nt = 0; nt < 8; ++nt) {
                    const f32x4 aL = *(const f32x4*)(ab + ((qt * 8 + nt) * 64 + lane) * 4);
                    #pragma unroll
                    for (int r = 0; r < 4; ++r) {
                        const int q = rbase + qt * 16 + g * 4 + r;
                        out[((size_t)h * SEQ + q) * DH + nt * 16 + l4] =
                            acc[qt][nt][r] * v0[r] + aL[r] * v1[r];
                    }
                }
            }
        }
        __syncthreads();
    }
}

// ---------------- scalar kernel (full fallback only; uses raw f32 K/V) ----------------
#define KT  32
#define LDK (DH + 4)
__global__ __launch_bounds__(256, 2)
void anystory_attn_scalar(const float* __restrict__ Q, const float* __restrict__ K,
                          const float* __restrict__ V, const float* __restrict__ ref_mask,
                          const float* __restrict__ routing, float* __restrict__ out, int row0)
{
    __shared__ float KsS[KT][LDK];
    __shared__ float VsS[KT][LDK];

    const int h    = blockIdx.y;
    const int r0   = row0 + blockIdx.x * 4;
    const int tid  = threadIdx.x;
    const int wave = tid >> 6;
    const int lane = tid & 63;
    const int key_l = lane & 31;
    const int half  = lane >> 5;
    const int row  = r0 + wave;

    int rs0, re0, rs1 = 0, re1 = 0;
    bool masked = false;
    if (r0 < TRI) { rs0 = 0; re0 = TRIR; masked = true; }
    else if (r0 < TRIR) {
        int c = (r0 - TRI) / (REFN / NC);
        rs0 = TRI + c * (REFN / NC); re0 = rs0 + (REFN / NC);
    } else { rs0 = TRE; re0 = TRI; rs1 = TRIR; re1 = SEQ; }

    float4 qreg[16];
    const float4* qptr = (const float4*)(Q + ((size_t)h * SEQ + row) * DH + half * 64);
    #pragma unroll
    for (int i = 0; i < 16; ++i) qreg[i] = qptr[i];

    float m = -1e30f, l = 0.f, acc0 = 0.f, acc1 = 0.f;

    for (int range = 0; range < 2; ++range) {
        const int ks = (range == 0) ? rs0 : rs1;
        const int ke = (range == 0) ? re0 : re1;
        for (int kt = ks; kt < ke; kt += KT) {
            __syncthreads();
            #pragma unroll
            for (int i = 0; i < 4; ++i) {
                int idx = tid + i * 256;
                int rr = idx >> 5, cc = (idx & 31) * 4;
                const float4 kv = ((const float4*)(K + ((size_t)h * SEQ + kt + rr) * DH))[idx & 31];
                const float4 vv = ((const float4*)(V + ((size_t)h * SEQ + kt + rr) * DH))[idx & 31];
                *(float4*)&KsS[rr][cc] = kv;
                *(float4*)&VsS[rr][cc] = vv;
            }
            __syncthreads();

            const int kglob = kt + key_l;
            float dot = 0.f;
            #pragma unroll
            for (int i = 0; i < 16; ++i) {
                float4 k4 = *(const float4*)&KsS[key_l][half * 64 + i * 4];
                dot += qreg[i].x * k4.x + qreg[i].y * k4.y + qreg[i].z * k4.z + qreg[i].w * k4.w;
            }
            dot += __shfl_xor(dot, 32);
            float logit = dot * SCALE;

            if (masked) {
                if (kglob >= TRI) {
                    logit += 1.5f + (ref_mask[(size_t)(kglob - TRI) * TRI + row] - 1.f) * 100.f;
                    if (row >= TRE)
                        logit += (routing[((kglob - TRI) >> 8) * IMG + (row - TRE)] - 1.f) * 100.f;
                } else if (kglob >= TXT && kglob < TRE && row >= TRE) {
                    logit += (routing[((kglob - TXT) >> 5) * IMG + (row - TRE)] - 1.f) * 100.f;
                }
            }

            float tm = logit;
            tm = fmaxf(tm, __shfl_xor(tm, 1));
            tm = fmaxf(tm, __shfl_xor(tm, 2));
            tm = fmaxf(tm, __shfl_xor(tm, 4));
            tm = fmaxf(tm, __shfl_xor(tm, 8));
            tm = fmaxf(tm, __shfl_xor(tm, 16));
            const float nm   = fmaxf(m, tm);
            const float corr = __expf(m - nm);
            const float p    = __expf(logit - nm);
            float ps = p;
            ps += __shfl_xor(ps, 1);
            ps += __shfl_xor(ps, 2);
            ps += __shfl_xor(ps, 4);
            ps += __shfl_xor(ps, 8);
            ps += __shfl_xor(ps, 16);
            l = l * corr + ps;
            acc0 *= corr; acc1 *= corr;
            m = nm;

            #pragma unroll
            for (int k = 0; k < KT; ++k) {
                const float pk = __shfl(p, k);
                acc0 += pk * VsS[k][lane];
                acc1 += pk * VsS[k][lane + 64];
            }
        }
    }

    const float inv = 1.f / l;
    float* op = out + ((size_t)h * SEQ + row) * DH;
    op[lane]      = acc0 * inv;
    op[lane + 64] = acc1 * inv;
}

extern "C" void kernel_launch(void* const* d_in, const int* in_sizes, int n_in,
                              void* d_out, int out_size, void* d_ws, size_t ws_size,
                              hipStream_t stream) {
    const float* Q        = (const float*)d_in[0];
    const float* K        = (const float*)d_in[1];
    const float* V        = (const float*)d_in[2];
    const float* ref_mask = (const float*)d_in[3];
    const float* routing  = (const float*)d_in[4];
    float* out = (float*)d_out;

    const size_t elems = (size_t)NH * SEQ * DH;
    const size_t need  = 2 * elems * sizeof(short);

    if (ws_size < need) {
        dim3 grid(SEQ / 4, NH);
        anystory_attn_scalar<<<grid, 256, 0, stream>>>(Q, K, V, ref_mask, routing, out, 0);
        return;
    }

    short* Kb  = (short*)d_ws;
    short* Vtg = Kb + elems;

    cvt_kv_kernel<<<dim3(SEQ / 16, NH), 256, 0, stream>>>(K, V, Kb, Vtg);

    // 26 block-cols per head (21 heavy, 1 router, 4 ref), head-major for XCD L2 locality
    attn_mfma<<<dim3(NH * 26), 512, 0, stream>>>(Q, Kb, Vtg, ref_mask, routing, out);
}

// Round 15
// 217.949 us; speedup vs baseline: 1.4353x; 1.4353x over previous
//
#include <hip/hip_runtime.h>
#include <hip/hip_bf16.h>

#define TXT   512
#define REDUX 64
#define IMG   2048
#define REFN  512
#define NC    2
#define SEQ   3168
#define DH    128
#define NH    24
#define TRE   576
#define TRI   2624
#define TRIR  3136
#define SCALE 0.08838834764831845f
#define L2E   1.4426950408889634f
#define QSC   (SCALE * L2E)          // scale folded with log2(e)
#define C100  (100.0f * L2E)         // 144.2695
#define CREF  (98.5f * L2E)          // 142.1055
#define THR2  (4.0f * L2E)           // defer-max threshold in log2 units

using f32x4  = __attribute__((ext_vector_type(4))) float;
using short8 = __attribute__((ext_vector_type(8))) short;

__device__ inline short f2bf(float x) {
    union { __hip_bfloat16 b; short s; } u;
    u.b = __float2bfloat16(x);
    return u.s;
}

__device__ inline void gload16(const short* g, short* l) {
    __builtin_amdgcn_global_load_lds(
        (const __attribute__((address_space(1))) unsigned int*)g,
        (__attribute__((address_space(3))) unsigned int*)l, 16, 0, 0);
}

// ---------------- fused pre-pass: K f32->bf16 linear, V f32->bf16 transposed+permuted ----
// Vt[h][d][pos] with key order permuted within each 64-key tile:
//   pos = ks2*32 + g*8 + i maps key lambda(g,i) = ks2*32 + (i<4 ? g*4+i : 16+g*4+(i-4)),
//   so the PV B-fragment for MFMA slot block g is one contiguous b128 chunk.
__global__ void cvt_kv_kernel(const float* __restrict__ K, const float* __restrict__ V,
                              short* __restrict__ Kb, short* __restrict__ Vt) {
    const int h   = blockIdx.y;
    const int tid = threadIdx.x;
    {
        const int base = ((h * SEQ + blockIdx.x * 16) * DH) >> 2;   // float4 idx
        #pragma unroll
        for (int j = 0; j < 2; ++j) {
            const int i = base + tid + j * 256;
            const float4 v = ((const float4*)K)[i];
            short4 o;
            o.x = f2bf(v.x); o.y = f2bf(v.y); o.z = f2bf(v.z); o.w = f2bf(v.w);
            ((short4*)Kb)[i] = o;
        }
    }
    {
        const int s8 = blockIdx.x * 2 + (tid >> 7);
        const int d  = tid & 127;
        const int s0 = s8 * 8;                       // 8 consecutive keys
        const float* src = V + ((size_t)h * SEQ + s0) * DH + d;
        short8 w;
        #pragma unroll
        for (int j = 0; j < 8; ++j) w[j] = f2bf(src[j * DH]);
        // lambda-permuted positions within the 64-key tile
        const int tb   = s0 & ~63;                   // tile base (tiles are 64-aligned)
        const int j0   = s0 & 63;                    // 0,8,16,...,56
        const int ks2  = j0 >> 5;
        const int jm   = j0 & 15;                    // 0 or 8
        const int hi   = (j0 >> 4) & 1;
        const int pos0 = ks2 * 32 + (jm >> 2) * 8 + hi * 4;
        short* dst = Vt + ((size_t)h * DH + d) * SEQ + tb;
        short4 lo4, hi4;
        lo4.x = w[0]; lo4.y = w[1]; lo4.z = w[2]; lo4.w = w[3];
        hi4.x = w[4]; hi4.y = w[5]; hi4.z = w[6]; hi4.w = w[7];
        *(short4*)(dst + pos0)     = lo4;            // keys j0+0..3
        *(short4*)(dst + pos0 + 8) = hi4;            // keys j0+4..7
    }
}

// ---------------- MFMA flash attention: swapped-QK, lane-local softmax ----------------
// Best-found configuration (R9): 8 waves x 16 q-rows, VGPR=64 (top occupancy band),
// 32KB LDS, swapped-QK lane-local softmax, lambda-permuted V for single-b128 PV frags.
// Falsified alternatives: split-K (R10, +traffic no TLP gain), 32q/wave (R11-R14: the
// extra 32 VGPRs of state always drops an occupancy band and loses more than the
// halved LDS traffic wins), counted-vmcnt pipeline (R7: breaks cross-block L2 convoy).
__global__ __launch_bounds__(512, 4)
void attn_mfma(const float* __restrict__ Q, const short* __restrict__ Kb,
               const short* __restrict__ Vtg, const float* __restrict__ ref_mask,
               const float* __restrict__ routing, float* __restrict__ out)
{
    __shared__ short Ks[64 * 128];     // [key][chunk^(key&7)] bf16
    __shared__ short Vs[128 * 64];     // [d][kc^(d&7)] bf16 (keys in lambda-permuted order)

    const int bid  = blockIdx.x;
    const int h    = bid % NH;          // same head -> same (bid%8) -> same XCD
    const int bx   = bid / NH;          // 0..25, heavy blocks dispatch first
    const int tid  = threadIdx.x;
    const int wave = tid >> 6, lane = tid & 63;
    const int g    = lane >> 4, l4 = lane & 15;

    int qbase, ks0 = 0, ntiles;
    bool masked = false, router = false;
    if (bx < 21)       { qbase = bx * 128; ntiles = 49; masked = true; }
    else if (bx == 21) { qbase = TRIR; ntiles = 33; router = true; }
    else {
        const int b2 = bx - 22;
        qbase = TRI + b2 * 128;
        ks0 = TRI + (b2 >> 1) * 256; ntiles = 4;
    }

    const int rbase = qbase + wave * 16;             // this wave's 16 q rows
    const bool valid = !(masked && rbase >= TRI) && !(router && wave >= 2);

    // ---- staging address precompute (pre-swizzled global source, linear LDS dest) ----
    const short* KbH = Kb  + (size_t)h * SEQ * DH;
    const short* VtH = Vtg + (size_t)h * DH * SEQ;
    int koff[2], vD[2], vKC[2], voff[2];
    #pragma unroll
    for (int j = 0; j < 2; ++j) {
        const int ci = tid + j * 512;
        const int kk = ci >> 4, kc = ci & 15;
        koff[j] = kk * 128 + ((kc ^ (kk & 7)) << 3);
        const int vd = ci >> 3, vk = ci & 7;
        vD[j] = vd; vKC[j] = vk;
        voff[j] = vd * SEQ + ((vk ^ (vd & 7)) << 3);
    }
    short* ksd0 = Ks + (size_t)(wave * 64) * 8;
    short* ksd1 = Ks + (size_t)(512 + wave * 64) * 8;
    short* vsd0 = Vs + (size_t)(wave * 64) * 8;
    short* vsd1 = Vs + (size_t)(512 + wave * 64) * 8;

    // ---- Q fragments (pre-scaled to log2 domain, bf16): row = l4, k-chunk = ks*4+g ----
    short8 qA[4];
    if (valid) {
        const int q = rbase + l4;
        const float* qp = Q + ((size_t)h * SEQ + q) * DH;
        #pragma unroll
        for (int ks = 0; ks < 4; ++ks) {
            const float4 a = *(const float4*)(qp + ks * 32 + g * 8);
            const float4 b = *(const float4*)(qp + ks * 32 + g * 8 + 4);
            short8 f;
            f[0] = f2bf(a.x * QSC); f[1] = f2bf(a.y * QSC);
            f[2] = f2bf(a.z * QSC); f[3] = f2bf(a.w * QSC);
            f[4] = f2bf(b.x * QSC); f[5] = f2bf(b.y * QSC);
            f[6] = f2bf(b.z * QSC); f[7] = f2bf(b.w * QSC);
            qA[ks] = f;
        }
    }

    f32x4 acc[8] = {};
    float m_run = -3.0e38f, l_run = 0.f;             // per q = rbase + l4 (lane-local)
    const int bsrc = (lane >> 4) << 2;               // shuffle source base g*4

    for (int t = 0; t < ntiles; ++t) {
        const int kt = masked ? t * 64
                     : (router ? (t < 32 ? TRE + t * 64 : TRIR) : ks0 + t * 64);
        const bool tail = router && (t == 32);       // only 32 of 64 keys valid
        __syncthreads();                             // A: previous tile consumed
        const short* kb = KbH + (size_t)kt * DH;
        const short* vb = VtH + kt;
        {
            const int ko0 = tail ? (koff[0] & 4095) : koff[0];
            const int ko1 = tail ? (koff[1] & 4095) : koff[1];
            gload16(kb + ko0, ksd0);
            gload16(kb + ko1, ksd1);
            const int vo0 = tail ? (vD[0] * SEQ + (((vKC[0] ^ (vD[0] & 7)) & 3) << 3)) : voff[0];
            const int vo1 = tail ? (vD[1] * SEQ + (((vKC[1] ^ (vD[1] & 7)) & 3) << 3)) : voff[1];
            gload16(vb + vo0, vsd0);
            gload16(vb + vo1, vsd1);
        }
        __syncthreads();                             // B: drains vmcnt + barrier

        if (!valid) continue;

        // ---- QK^T swapped: s[nt][r] = S[key = nt*16 + g*4 + r][q = rbase + l4] ----
        f32x4 s[4] = {};
        __builtin_amdgcn_s_setprio(1);
        #pragma unroll
        for (int nt = 0; nt < 4; ++nt) {
            const int key = nt * 16 + l4;
            #pragma unroll
            for (int ks = 0; ks < 4; ++ks) {
                const short8 kB = *(const short8*)(Ks + key * 128 + (((ks * 4 + g) ^ (key & 7)) << 3));
                s[nt] = __builtin_amdgcn_mfma_f32_16x16x32_bf16(kB, qA[ks], s[nt], 0, 0, 0);
            }
        }
        __builtin_amdgcn_s_setprio(0);

        // ---- masks (f32 exact, log2 domain), swapped orientation ----
        if (masked) {
            if (kt >= TRI) {                         // ref-key tiles
                const int cr = (kt - TRI) >> 8;
                const int q  = rbase + l4;
                const bool hr = rbase >= TRE;
                float radd = 0.f;
                if (hr) radd = routing[cr * IMG + (q - TRE)] * C100 - C100;
                const int j0 = kt - TRI + g * 4;
                #pragma unroll
                for (int nt = 0; nt < 4; ++nt)
                    #pragma unroll
                    for (int r = 0; r < 4; ++r) {
                        const float rmv = ref_mask[(size_t)(j0 + nt * 16 + r) * TRI + q];
                        s[nt][r] += rmv * C100 - CREF + radd;
                    }
            } else if (kt == TXT) {                  // redux-key tile
                if (rbase >= TRE) {
                    const int q = rbase + l4;
                    const float a0 = routing[q - TRE] * C100 - C100;
                    const float a1 = routing[IMG + q - TRE] * C100 - C100;
                    #pragma unroll
                    for (int nt = 0; nt < 4; ++nt)
                        #pragma unroll
                        for (int r = 0; r < 4; ++r)
                            s[nt][r] += (nt >> 1) ? a1 : a0;
                }
            }
        }
        if (tail) {                                  // router tail: keys >= SEQ invalid
            #pragma unroll
            for (int r = 0; r < 4; ++r) { s[2][r] = -3.0e38f; s[3][r] = -3.0e38f; }
        }

        // ---- softmax: lane-local (16 keys in-reg) + 2 cross-group shuffles ----
        float mx = fmaxf(fmaxf(s[0][0], s[0][1]), fmaxf(s[0][2], s[0][3]));
        mx = fmaxf(mx, fmaxf(fmaxf(s[1][0], s[1][1]), fmaxf(s[1][2], s[1][3])));
        mx = fmaxf(mx, fmaxf(fmaxf(s[2][0], s[2][1]), fmaxf(s[2][2], s[2][3])));
        mx = fmaxf(mx, fmaxf(fmaxf(s[3][0], s[3][1]), fmaxf(s[3][2], s[3][3])));
        mx = fmaxf(mx, __shfl_xor(mx, 16));
        mx = fmaxf(mx, __shfl_xor(mx, 32));

        if (__any(mx - m_run > THR2)) {              // defer-max rescale (rare)
            const float mn    = fmaxf(m_run, mx);
            const float corrq = exp2f(m_run - mn);
            m_run = mn;
            l_run *= corrq;
            f32x4 corr;                               // broadcast corr to acc rows q=g*4+r
            #pragma unroll
            for (int r = 0; r < 4; ++r) corr[r] = __shfl(corrq, bsrc + r);
            #pragma unroll
            for (int nt = 0; nt < 8; ++nt)
                #pragma unroll
                for (int r = 0; r < 4; ++r) acc[nt][r] *= corr[r];
        }

        float rsum = 0.f;
        #pragma unroll
        for (int nt = 0; nt < 4; ++nt)
            #pragma unroll
            for (int r = 0; r < 4; ++r) {
                s[nt][r] = exp2f(s[nt][r] - m_run);
                rsum += s[nt][r];
            }
        rsum += __shfl_xor(rsum, 16);
        rsum += __shfl_xor(rsum, 32);
        l_run += rsum;

        // ---- pack P in-lane: pA slots = lambda(g,i) = ks2*32 + (i<4 ? g*4+i : 16+g*4+i-4) ----
        short8 pA0, pA1;
        #pragma unroll
        for (int j = 0; j < 4; ++j) {
            pA0[j]     = f2bf(s[0][j]);
            pA0[4 + j] = f2bf(s[1][j]);
            pA1[j]     = f2bf(s[2][j]);
            pA1[4 + j] = f2bf(s[3][j]);
        }

        // ---- PV: Vs is lambda-permuted, so B-fragment = one b128 chunk read ----
        __builtin_amdgcn_s_setprio(1);
        #pragma unroll
        for (int ks2 = 0; ks2 < 2; ++ks2) {
            const short8 pa = ks2 ? pA1 : pA0;
            const int kc = ks2 * 4 + g;              // permuted chunk holding lambda(g,0..7)
            #pragma unroll
            for (int nt = 0; nt < 8; ++nt) {
                const int d = nt * 16 + l4;
                const short8 vB = *(const short8*)(Vs + d * 64 + ((kc ^ (d & 7)) << 3));
                acc[nt] = __builtin_amdgcn_mfma_f32_16x16x32_bf16(pa, vB, acc[nt], 0, 0, 0);
            }
        }
        __builtin_amdgcn_s_setprio(0);
    }

    if (valid) {
        f32x4 linv;                                  // 1/l for acc rows q = g*4+r
        #pragma unroll
        for (int r = 0; r < 4; ++r) linv[r] = 1.0f / __shfl(l_run, bsrc + r);
        #pragma unroll
        for (int nt = 0; nt < 8; ++nt)
            #pragma unroll
            for (int r = 0; r < 4; ++r) {
                const int q = rbase + g * 4 + r;
                out[((size_t)h * SEQ + q) * DH + nt * 16 + l4] = acc[nt][r] * linv[r];
            }
    }
}

// ---------------- scalar kernel (full fallback only; uses raw f32 K/V) ----------------
#define KT  32
#define LDK (DH + 4)
__global__ __launch_bounds__(256, 2)
void anystory_attn_scalar(const float* __restrict__ Q, const float* __restrict__ K,
                          const float* __restrict__ V, const float* __restrict__ ref_mask,
                          const float* __restrict__ routing, float* __restrict__ out, int row0)
{
    __shared__ float KsS[KT][LDK];
    __shared__ float VsS[KT][LDK];

    const int h    = blockIdx.y;
    const int r0   = row0 + blockIdx.x * 4;
    const int tid  = threadIdx.x;
    const int wave = tid >> 6;
    const int lane = tid & 63;
    const int key_l = lane & 31;
    const int half  = lane >> 5;
    const int row  = r0 + wave;

    int rs0, re0, rs1 = 0, re1 = 0;
    bool masked = false;
    if (r0 < TRI) { rs0 = 0; re0 = TRIR; masked = true; }
    else if (r0 < TRIR) {
        int c = (r0 - TRI) / (REFN / NC);
        rs0 = TRI + c * (REFN / NC); re0 = rs0 + (REFN / NC);
    } else { rs0 = TRE; re0 = TRI; rs1 = TRIR; re1 = SEQ; }

    float4 qreg[16];
    const float4* qptr = (const float4*)(Q + ((size_t)h * SEQ + row) * DH + half * 64);
    #pragma unroll
    for (int i = 0; i < 16; ++i) qreg[i] = qptr[i];

    float m = -1e30f, l = 0.f, acc0 = 0.f, acc1 = 0.f;

    for (int range = 0; range < 2; ++range) {
        const int ks = (range == 0) ? rs0 : rs1;
        const int ke = (range == 0) ? re0 : re1;
        for (int kt = ks; kt < ke; kt += KT) {
            __syncthreads();
            #pragma unroll
            for (int i = 0; i < 4; ++i) {
                int idx = tid + i * 256;
                int rr = idx >> 5, cc = (idx & 31) * 4;
                const float4 kv = ((const float4*)(K + ((size_t)h * SEQ + kt + rr) * DH))[idx & 31];
                const float4 vv = ((const float4*)(V + ((size_t)h * SEQ + kt + rr) * DH))[idx & 31];
                *(float4*)&KsS[rr][cc] = kv;
                *(float4*)&VsS[rr][cc] = vv;
            }
            __syncthreads();

            const int kglob = kt + key_l;
            float dot = 0.f;
            #pragma unroll
            for (int i = 0; i < 16; ++i) {
                float4 k4 = *(const float4*)&KsS[key_l][half * 64 + i * 4];
                dot += qreg[i].x * k4.x + qreg[i].y * k4.y + qreg[i].z * k4.z + qreg[i].w * k4.w;
            }
            dot += __shfl_xor(dot, 32);
            float logit = dot * SCALE;

            if (masked) {
                if (kglob >= TRI) {
                    logit += 1.5f + (ref_mask[(size_t)(kglob - TRI) * TRI + row] - 1.f) * 100.f;
                    if (row >= TRE)
                        logit += (routing[((kglob - TRI) >> 8) * IMG + (row - TRE)] - 1.f) * 100.f;
                } else if (kglob >= TXT && kglob < TRE && row >= TRE) {
                    logit += (routing[((kglob - TXT) >> 5) * IMG + (row - TRE)] - 1.f) * 100.f;
                }
            }

            float tm = logit;
            tm = fmaxf(tm, __shfl_xor(tm, 1));
            tm = fmaxf(tm, __shfl_xor(tm, 2));
            tm = fmaxf(tm, __shfl_xor(tm, 4));
            tm = fmaxf(tm, __shfl_xor(tm, 8));
            tm = fmaxf(tm, __shfl_xor(tm, 16));
            const float nm   = fmaxf(m, tm);
            const float corr = __expf(m - nm);
            const float p    = __expf(logit - nm);
            float ps = p;
            ps += __shfl_xor(ps, 1);
            ps += __shfl_xor(ps, 2);
            ps += __shfl_xor(ps, 4);
            ps += __shfl_xor(ps, 8);
            ps += __shfl_xor(ps, 16);
            l = l * corr + ps;
            acc0 *= corr; acc1 *= corr;
            m = nm;

            #pragma unroll
            for (int k = 0; k < KT; ++k) {
                const float pk = __shfl(p, k);
                acc0 += pk * VsS[k][lane];
                acc1 += pk * VsS[k][lane + 64];
            }
        }
    }

    const float inv = 1.f / l;
    float* op = out + ((size_t)h * SEQ + row) * DH;
    op[lane]      = acc0 * inv;
    op[lane + 64] = acc1 * inv;
}

extern "C" void kernel_launch(void* const* d_in, const int* in_sizes, int n_in,
                              void* d_out, int out_size, void* d_ws, size_t ws_size,
                              hipStream_t stream) {
    const float* Q        = (const float*)d_in[0];
    const float* K        = (const float*)d_in[1];
    const float* V        = (const float*)d_in[2];
    const float* ref_mask = (const float*)d_in[3];
    const float* routing  = (const float*)d_in[4];
    float* out = (float*)d_out;

    const size_t elems = (size_t)NH * SEQ * DH;
    const size_t need  = 2 * elems * sizeof(short);

    if (ws_size < need) {
        dim3 grid(SEQ / 4, NH);
        anystory_attn_scalar<<<grid, 256, 0, stream>>>(Q, K, V, ref_mask, routing, out, 0);
        return;
    }

    short* Kb  = (short*)d_ws;
    short* Vtg = Kb + elems;

    cvt_kv_kernel<<<dim3(SEQ / 16, NH), 256, 0, stream>>>(K, V, Kb, Vtg);

    // 26 block-cols per head (21 heavy, 1 router, 4 ref), head-major for XCD L2 locality
    attn_mfma<<<dim3(NH * 26), 512, 0, stream>>>(Q, Kb, Vtg, ref_mask, routing, out);
}